// Round 14
// baseline (6016.458 us; speedup 1.0000x reference)
//
#include <hip/hip_runtime.h>
#include <float.h>

#define BB    2048
#define DD    128
#define KK    256
#define HH    256
#define MM    8
#define SS    7
#define BEAMW 16
#define AA    8
#define WM    64   // candidates per mlp block

typedef _Float16 f16x8 __attribute__((ext_vector_type(8)));
typedef float    f32x4 __attribute__((ext_vector_type(4)));

// swizzled index into a [rows][32] fp32 LDS tile (prefilter only)
#define HSWZ(row, m) (((row) << 5) + ((((m) + ((((row) >> 3)) << 2))) & 31))

// halfword offset into a [WM][256] f16 LDS tile, 8-halfword blocks XOR-swizzled
__device__ __forceinline__ int hoff(int m, int j) {
  return m * 256 + ((((j >> 3) ^ (m & 7)) << 3) | (j & 7));
}

// ---------------------------------------------------------------- step 0
__global__ __launch_bounds__(64) void step0_kernel(
    const float* __restrict__ x, const float* __restrict__ cb,
    float* __restrict__ xhat, int* __restrict__ codes)
{
  int b = blockIdx.x, l = threadIdx.x;
  __shared__ float xs[DD];
  xs[l]      = x[b * DD + l];
  xs[l + 64] = x[b * DD + 64 + l];
  __syncthreads();
  float dist[4];
#pragma unroll
  for (int q = 0; q < 4; ++q) {
    const float* row = cb + (size_t)(q * 64 + l) * DD;
    float dot = 0.f, nrm = 0.f;
#pragma unroll 8
    for (int d = 0; d < DD; d += 4) {
      float4 c = *(const float4*)(row + d);
      dot += c.x * xs[d] + c.y * xs[d + 1] + c.z * xs[d + 2] + c.w * xs[d + 3];
      nrm += c.x * c.x + c.y * c.y + c.z * c.z + c.w * c.w;
    }
    dist[q] = nrm - 2.f * dot;
  }
  for (int it = 0; it < BEAMW; ++it) {
    float bv = dist[0]; int bi = l;
#pragma unroll
    for (int q = 1; q < 4; ++q) {
      if (dist[q] < bv) { bv = dist[q]; bi = q * 64 + l; }
    }
#pragma unroll
    for (int mmk = 1; mmk < 64; mmk <<= 1) {
      float ov = __shfl_xor(bv, mmk);
      int   oi = __shfl_xor(bi, mmk);
      if (ov < bv || (ov == bv && oi < bi)) { bv = ov; bi = oi; }
    }
    const float* crow = cb + (size_t)bi * DD;
    float2 v = *(const float2*)(crow + l * 2);
    *(float2*)(xhat + (size_t)(b * BEAMW + it) * DD + l * 2) = v;
    if (l == 0) codes[(b * BEAMW + it) * MM] = bi;
    if (l == (bi & 63)) dist[bi >> 6] = FLT_MAX;
  }
}

// --------------------- upfront: rq^T + norms for ALL steps
__global__ __launch_bounds__(128) void rqprep_kernel(
    const float* __restrict__ rq, float* __restrict__ rqT7, float* __restrict__ rqn7)
{
  int s = blockIdx.x >> 8, k = blockIdx.x & 255, d = threadIdx.x;
  float v = rq[(size_t)s * KK * DD + k * DD + d];
  rqT7[(size_t)s * DD * KK + d * KK + k] = v;
  float p = v * v;
#pragma unroll
  for (int mmk = 1; mmk < 64; mmk <<= 1) p += __shfl_xor(p, mmk);
  __shared__ float ps[2];
  if ((d & 63) == 0) ps[d >> 6] = p;
  __syncthreads();
  if (d == 0) rqn7[s * KK + k] = ps[0] + ps[1];
}

// --------------------- upfront: per-code linear-path table for ALL steps
__global__ __launch_bounds__(256) void codeterm_kernel(
    const float* __restrict__ cb, const float* __restrict__ Win,
    const float* __restrict__ bin, const float* __restrict__ Wcat,
    const float* __restrict__ bcat, float* __restrict__ ct7)
{
  int s = blockIdx.x >> 8, k = blockIdx.x & 255, j = threadIdx.x;
  const float* cbstep = cb + (size_t)(s + 1) * KK * DD;
  const float* WinS   = Win + (size_t)s * DD * HH;
  const float* WcatS  = Wcat + (size_t)s * 384 * HH;
  __shared__ float crow[DD];
  __shared__ float h1[HH];
  if (j < DD) crow[j] = cbstep[k * DD + j];
  __syncthreads();
  float a = bin[s * HH + j];
  for (int d = 0; d < DD; ++d) a += crow[d] * WinS[d * HH + j];
  h1[j] = a;
  __syncthreads();
  float c = bcat[s * HH + j];
  for (int t = 0; t < HH; ++t) c += h1[t] * WcatS[t * HH + j];
  ct7[(size_t)s * KK * HH + k * HH + j] = c;
}

// --------------------- upfront: pack weights (hi/lo f16 frags) for ALL steps
__global__ __launch_bounds__(256) void wpack_kernel(
    const float* __restrict__ W1, const float* __restrict__ W2,
    const float* __restrict__ Wout, const float* __restrict__ Wcat,
    _Float16* __restrict__ wAh7, _Float16* __restrict__ wAl7,
    _Float16* __restrict__ woh7, _Float16* __restrict__ wol7,
    _Float16* __restrict__ wch7, _Float16* __restrict__ wcl7)
{
  int tg = blockIdx.x * 256 + threadIdx.x;
  int s = tg / 40960;
  int t = tg % 40960;
  const float* src; _Float16 *dh, *dl;
  int N, r;
  if (t < 32768) {
    int mi = t >> 13; r = t & 8191;
    src = (mi & 1 ? W2 : W1) + (size_t)s * 2 * HH * HH + (size_t)(mi >> 1) * HH * HH;
    dh = wAh7 + (size_t)s * 262144 + (size_t)mi * 65536;
    dl = wAl7 + (size_t)s * 262144 + (size_t)mi * 65536;
    N = 256;
  } else if (t < 36864) {
    r = t - 32768;
    src = Wout + (size_t)s * HH * DD;
    dh = woh7 + (size_t)s * 32768; dl = wol7 + (size_t)s * 32768;
    N = 128;
  } else {
    r = t - 36864;
    src = Wcat + (size_t)s * 384 * HH + (size_t)256 * HH;
    dh = wch7 + (size_t)s * 32768; dl = wcl7 + (size_t)s * 32768;
    N = 256;
  }
  int l = r & 63;
  int nct = N >> 4;
  int c = (r >> 6) & (nct - 1);
  int q = r / (64 * nct);
  int k0 = q * 32 + (l >> 4) * 8;
  int col = c * 16 + (l & 15);
  size_t fo = (size_t)r * 8;
#pragma unroll
  for (int j = 0; j < 8; ++j) {
    float v = src[(size_t)(k0 + j) * N + col];
    _Float16 hi = (_Float16)v;
    dh[fo + j] = hi;
    dl[fo + j] = (_Float16)((v - (float)hi) * 2048.0f);
  }
}

// ------------- per-step: xterm = xhat @ Wcat2 -> xtg[32768][256] (f32)
__global__ __launch_bounds__(256) void xterm_kernel(
    const float* __restrict__ xhat,
    const _Float16* __restrict__ wch, const _Float16* __restrict__ wcl,
    float* __restrict__ xtg)
{
  int tid = threadIdx.x;
  int l = tid & 63, w = tid >> 6;
  int lg = l >> 4, lr = l & 15;
  int r0 = blockIdx.x * 16;
  const f32x4 z4 = {0.f, 0.f, 0.f, 0.f};
  f32x4 a1[4], a2[4];
#pragma unroll
  for (int c = 0; c < 4; ++c) { a1[c] = z4; a2[c] = z4; }
  for (int q = 0; q < 4; ++q) {
    const float* ap = xhat + (size_t)(r0 + lr) * DD + q * 32 + lg * 8;
    float4 f0 = *(const float4*)ap;
    float4 f1 = *(const float4*)(ap + 4);
    float fv[8] = {f0.x, f0.y, f0.z, f0.w, f1.x, f1.y, f1.z, f1.w};
    f16x8 Ah, Al;
#pragma unroll
    for (int j = 0; j < 8; ++j) {
      _Float16 hi = (_Float16)fv[j];
      Ah[j] = hi;
      Al[j] = (_Float16)((fv[j] - (float)hi) * 2048.0f);
    }
#pragma unroll
    for (int c = 0; c < 4; ++c) {
      size_t boff = ((size_t)(q * 16 + w * 4 + c) * 64 + l) * 8;
      f16x8 Bh = *(const f16x8*)&wch[boff];
      f16x8 Bl = *(const f16x8*)&wcl[boff];
      a1[c] = __builtin_amdgcn_mfma_f32_16x16x32_f16(Ah, Bh, a1[c], 0, 0, 0);
      a2[c] = __builtin_amdgcn_mfma_f32_16x16x32_f16(Al, Bh, a2[c], 0, 0, 0);
      a2[c] = __builtin_amdgcn_mfma_f32_16x16x32_f16(Ah, Bl, a2[c], 0, 0, 0);
    }
  }
#pragma unroll
  for (int c = 0; c < 4; ++c) {
    int col = (w * 4 + c) * 16 + lr;
#pragma unroll
    for (int r = 0; r < 4; ++r) {
      int row = r0 + lg * 4 + r;
      xtg[(size_t)row * 256 + col] = a1[c][r] + a2[c][r] * (1.0f / 2048.0f);
    }
  }
}

// --------------------- per-step: distance prefilter + top-8 per (b,f)
__global__ __launch_bounds__(256) void prefilter_kernel(
    const float* __restrict__ x, const float* __restrict__ xhat,
    const float* __restrict__ rqT, const float* __restrict__ rqn,
    int* __restrict__ topc)
{
  __shared__ float xtT[DD * 32];
  __shared__ float distb[32 * KK];
  int tid = threadIdx.x;
  int bf0 = blockIdx.x * 32;
  for (int i = 0; i < 16; ++i) {
    int idx = tid + i * 256;
    int d = idx >> 5, r = idx & 31;
    int bf = bf0 + r;
    xtT[HSWZ(d, r)] = x[(bf >> 4) * DD + d] - xhat[(size_t)bf * DD + d];
  }
  __syncthreads();
  int jb = tid & 31, mb = tid >> 5;
  float acc[4][8];
#pragma unroll
  for (int i = 0; i < 4; ++i)
#pragma unroll
    for (int jj = 0; jj < 8; ++jj) acc[i][jj] = 0.f;
  for (int d = 0; d < DD; ++d) {
    float4 hv = *(float4*)&xtT[HSWZ(d, mb * 4)];
    float4 w0 = *(const float4*)&rqT[d * KK + jb * 8];
    float4 w1 = *(const float4*)&rqT[d * KK + jb * 8 + 4];
    float hvv[4] = {hv.x, hv.y, hv.z, hv.w};
    float wv[8]  = {w0.x, w0.y, w0.z, w0.w, w1.x, w1.y, w1.z, w1.w};
#pragma unroll
    for (int i = 0; i < 4; ++i)
#pragma unroll
      for (int jj = 0; jj < 8; ++jj) acc[i][jj] += hvv[i] * wv[jj];
  }
#pragma unroll
  for (int i = 0; i < 4; ++i) {
    int r = mb * 4 + i;
#pragma unroll
    for (int jj = 0; jj < 8; ++jj) {
      int k = jb * 8 + jj;
      distb[r * KK + k] = rqn[k] - 2.f * acc[i][jj];
    }
  }
  __syncthreads();
  int wv2 = tid >> 6, lane = tid & 63;
  for (int rr = 0; rr < 8; ++rr) {
    int r = wv2 * 8 + rr;
    float v[4];
#pragma unroll
    for (int q = 0; q < 4; ++q) v[q] = distb[r * KK + lane + q * 64];
    int bfr = bf0 + r;
    for (int it = 0; it < AA; ++it) {
      float bv = v[0]; int bi = lane;
#pragma unroll
      for (int q = 1; q < 4; ++q) {
        if (v[q] < bv) { bv = v[q]; bi = q * 64 + lane; }
      }
#pragma unroll
      for (int mmk = 1; mmk < 64; mmk <<= 1) {
        float ov = __shfl_xor(bv, mmk);
        int   oi = __shfl_xor(bi, mmk);
        if (ov < bv || (ov == bv && oi < bi)) { bv = ov; bi = oi; }
      }
      if (lane == (bi & 63)) v[bi >> 6] = FLT_MAX;
      if (lane == 0) topc[bfr * AA + it] = bi;
    }
  }
}

// ----------------------- per-step: fused residual MLP via split-f16 MFMA
// 64 candidates / 1024-thread block (16 waves, wave w owns coltile w).
// Separate u buffer (128 KB LDS) -> 2 barriers/layer; residual h carried in
// registers (hres) -> no LDS res re-reads.
__global__ __launch_bounds__(1024, 4) void mlp_kernel(
    const float* __restrict__ x, const float* __restrict__ xhat,
    const int* __restrict__ topc, const float* __restrict__ ct,
    const float* __restrict__ cbstep, const float* __restrict__ xtg,
    const _Float16* __restrict__ wAh, const _Float16* __restrict__ wAl,
    const _Float16* __restrict__ woh, const _Float16* __restrict__ wol,
    const float* __restrict__ b1a, const float* __restrict__ b2a,
    const float* __restrict__ bout,
    float* __restrict__ cand, float* __restrict__ d2g)
{
  __shared__ _Float16 hhi[WM * 256], hlo[WM * 256];   // 64 KB  h
  __shared__ _Float16 uhi[WM * 256], ulo[WM * 256];   // 64 KB  u
  __shared__ float xs[DD];
  __shared__ float pd2[WM][8];
  __shared__ int   cl[WM];

  int tid = threadIdx.x;
  int l = tid & 63, w = tid >> 6;          // w in [0,16)
  int lg = l >> 4, lr = l & 15;
  int bf0 = blockIdx.x * 8;               // 8 beam elems per block
  int b = bf0 >> 4;
  const f32x4 z4 = {0.f, 0.f, 0.f, 0.f};

  if (tid < WM) cl[tid] = topc[bf0 * AA + tid];
  if (tid < DD) xs[tid] = x[b * DD + tid];
  __syncthreads();

  // column ownership: wave w -> coltile w of N=256
  int j0 = w * 16 + lr;

  // ---- h_init own slots: ct[cl[m]][j0] + xtg[...][j0]; keep in hres regs
  float hres[4][4];
#pragma unroll
  for (int rt = 0; rt < 4; ++rt)
#pragma unroll
    for (int r = 0; r < 4; ++r) {
      int m = rt * 16 + lg * 4 + r;
      float v = ct[cl[m] * HH + j0] + xtg[(size_t)(bf0 + (m >> 3)) * 256 + j0];
      hres[rt][r] = v;
      _Float16 hi = (_Float16)v;
      int off = hoff(m, j0);
      hhi[off] = hi;
      hlo[off] = (_Float16)((v - (float)hi) * 2048.0f);
    }
  __syncthreads();   // h visible

  // ---- residual layers
  for (int lay = 0; lay < 2; ++lay) {
    const _Float16* W1h = wAh + (size_t)(lay * 2 + 0) * 65536;
    const _Float16* W1l = wAl + (size_t)(lay * 2 + 0) * 65536;
    const _Float16* W2h = wAh + (size_t)(lay * 2 + 1) * 65536;
    const _Float16* W2l = wAl + (size_t)(lay * 2 + 1) * 65536;

    // GEMM1: u = relu(h @ W1 + b1)
    f32x4 a1[4], a2[4];
#pragma unroll
    for (int rt = 0; rt < 4; ++rt) { a1[rt] = z4; a2[rt] = z4; }
    for (int q = 0; q < 8; ++q) {
      size_t boff = ((size_t)(q * 16 + w) * 64 + l) * 8;
      f16x8 Bh = *(const f16x8*)&W1h[boff];
      f16x8 Bl = *(const f16x8*)&W1l[boff];
#pragma unroll
      for (int rt = 0; rt < 4; ++rt) {
        int arow = rt * 16 + lr;
        int aoff = arow * 256 + (((q * 4 + lg) ^ (arow & 7)) << 3);
        f16x8 Ah = *(f16x8*)&hhi[aoff];
        f16x8 Al = *(f16x8*)&hlo[aoff];
        a1[rt] = __builtin_amdgcn_mfma_f32_16x16x32_f16(Ah, Bh, a1[rt], 0, 0, 0);
        a2[rt] = __builtin_amdgcn_mfma_f32_16x16x32_f16(Al, Bh, a2[rt], 0, 0, 0);
        a2[rt] = __builtin_amdgcn_mfma_f32_16x16x32_f16(Ah, Bl, a2[rt], 0, 0, 0);
      }
    }
    // epilogue: write u into the SEPARATE u buffer (no pre-barrier needed)
    {
      float bj = b1a[lay * HH + j0];
#pragma unroll
      for (int rt = 0; rt < 4; ++rt)
#pragma unroll
        for (int r = 0; r < 4; ++r) {
          int m = rt * 16 + lg * 4 + r;
          float u = fmaxf(a1[rt][r] + a2[rt][r] * (1.0f / 2048.0f) + bj, 0.f);
          _Float16 hi = (_Float16)u;
          int off = hoff(m, j0);
          uhi[off] = hi;
          ulo[off] = (_Float16)((u - (float)hi) * 2048.0f);
        }
    }
    __syncthreads();   // u visible; all GEMM1 h-reads done

    // GEMM2: h' = hres + u @ W2 + b2 (acc init from registers)
#pragma unroll
    for (int rt = 0; rt < 4; ++rt) {
#pragma unroll
      for (int r = 0; r < 4; ++r) a1[rt][r] = hres[rt][r];
      a2[rt] = z4;
    }
    for (int q = 0; q < 8; ++q) {
      size_t boff = ((size_t)(q * 16 + w) * 64 + l) * 8;
      f16x8 Bh = *(const f16x8*)&W2h[boff];
      f16x8 Bl = *(const f16x8*)&W2l[boff];
#pragma unroll
      for (int rt = 0; rt < 4; ++rt) {
        int arow = rt * 16 + lr;
        int aoff = arow * 256 + (((q * 4 + lg) ^ (arow & 7)) << 3);
        f16x8 Ah = *(f16x8*)&uhi[aoff];
        f16x8 Al = *(f16x8*)&ulo[aoff];
        a1[rt] = __builtin_amdgcn_mfma_f32_16x16x32_f16(Ah, Bh, a1[rt], 0, 0, 0);
        a2[rt] = __builtin_amdgcn_mfma_f32_16x16x32_f16(Al, Bh, a2[rt], 0, 0, 0);
        a2[rt] = __builtin_amdgcn_mfma_f32_16x16x32_f16(Ah, Bl, a2[rt], 0, 0, 0);
      }
    }
    // epilogue: h' -> hres regs + h buffer (no one reads h during GEMM2)
    {
      float bj = b2a[lay * HH + j0];
#pragma unroll
      for (int rt = 0; rt < 4; ++rt)
#pragma unroll
        for (int r = 0; r < 4; ++r) {
          int m = rt * 16 + lg * 4 + r;
          float v = a1[rt][r] + a2[rt][r] * (1.0f / 2048.0f) + bj;
          hres[rt][r] = v;
          _Float16 hi = (_Float16)v;
          int off = hoff(m, j0);
          hhi[off] = hi;
          hlo[off] = (_Float16)((v - (float)hi) * 2048.0f);
        }
    }
    __syncthreads();   // h' visible
  }

  // ---- out stage: cand = h @ W_out + b_out + cw_res + xhat; d2 scoring
  // N=128 -> coltile c8 = w&7; row-half mh = w>>3 covers rts {2mh, 2mh+1}
  int c8 = w & 7, mh = w >> 3;
  f32x4 o1[2], o2[2];
  o1[0] = z4; o1[1] = z4; o2[0] = z4; o2[1] = z4;
  for (int q = 0; q < 8; ++q) {
    size_t boff = ((size_t)(q * 8 + c8) * 64 + l) * 8;
    f16x8 Bh = *(const f16x8*)&woh[boff];
    f16x8 Bl = *(const f16x8*)&wol[boff];
#pragma unroll
    for (int rr = 0; rr < 2; ++rr) {
      int arow = (mh * 2 + rr) * 16 + lr;
      int aoff = arow * 256 + (((q * 4 + lg) ^ (arow & 7)) << 3);
      f16x8 Ah = *(f16x8*)&hhi[aoff];
      f16x8 Al = *(f16x8*)&hlo[aoff];
      o1[rr] = __builtin_amdgcn_mfma_f32_16x16x32_f16(Ah, Bh, o1[rr], 0, 0, 0);
      o2[rr] = __builtin_amdgcn_mfma_f32_16x16x32_f16(Al, Bh, o2[rr], 0, 0, 0);
      o2[rr] = __builtin_amdgcn_mfma_f32_16x16x32_f16(Ah, Bl, o2[rr], 0, 0, 0);
    }
  }
  int ci0 = (blockIdx.x & 1) * WM;
  int d = c8 * 16 + lr;
  float bo = bout[d];
  float xsd = xs[d];
#pragma unroll
  for (int rr = 0; rr < 2; ++rr) {
    int rt = mh * 2 + rr;
    float p[4];
#pragma unroll
    for (int r = 0; r < 4; ++r) {
      int m = rt * 16 + lg * 4 + r;
      float v = o1[rr][r] + o2[rr][r] * (1.0f / 2048.0f) + bo
              + cbstep[(size_t)cl[m] * DD + d]
              + xhat[(size_t)(bf0 + (m >> 3)) * DD + d];
      cand[((size_t)(b * 128 + ci0 + m)) * DD + d] = v;
      p[r] = v * (v - 2.f * xsd);
    }
#pragma unroll
    for (int mk = 1; mk < 16; mk <<= 1) {
#pragma unroll
      for (int r = 0; r < 4; ++r) p[r] += __shfl_xor(p[r], mk);
    }
    if (lr == 0) {
#pragma unroll
      for (int r = 0; r < 4; ++r) pd2[rt * 16 + lg * 4 + r][c8] = p[r];
    }
  }
  __syncthreads();
  if (tid < WM) {
    float s = 0.f;
#pragma unroll
    for (int ww = 0; ww < 8; ++ww) s += pd2[tid][ww];
    d2g[b * 128 + ci0 + tid] = s;
  }
}

// --------------------------- per-step: top-F_out prune + gather update
__global__ __launch_bounds__(64) void topk_update_kernel(
    const float* __restrict__ d2g, const float* __restrict__ cand,
    const int* __restrict__ codes_in, const int* __restrict__ topc,
    float* __restrict__ xhat_out, int* __restrict__ codes_out,
    int fout, int spos)
{
  int b = blockIdx.x, lane = threadIdx.x;
  float v0 = d2g[b * 128 + lane];
  float v1 = d2g[b * 128 + 64 + lane];
  for (int r = 0; r < fout; ++r) {
    float bv = v0; int bi = lane;
    if (v1 < bv) { bv = v1; bi = 64 + lane; }
#pragma unroll
    for (int mmk = 1; mmk < 64; mmk <<= 1) {
      float ov = __shfl_xor(bv, mmk);
      int   oi = __shfl_xor(bi, mmk);
      if (ov < bv || (ov == bv && oi < bi)) { bv = ov; bi = oi; }
    }
    int parent = bi >> 3, a = bi & 7;
    if (lane < MM) {
      int valc = (lane == spos) ? topc[(b * BEAMW + parent) * AA + a]
                                : codes_in[(b * BEAMW + parent) * MM + lane];
      codes_out[(b * BEAMW + r) * MM + lane] = valc;
    }
    const float* src = cand + ((size_t)(b * 128 + bi)) * DD;
    float2 t = *(const float2*)(src + lane * 2);
    *(float2*)(xhat_out + (size_t)(b * BEAMW + r) * DD + lane * 2) = t;
    if (bi < 64) { if (lane == bi) v0 = FLT_MAX; }
    else         { if (lane == bi - 64) v1 = FLT_MAX; }
  }
}

// ---------------------------------------------------------------- output
__global__ __launch_bounds__(64) void finalize_kernel(
    const int* __restrict__ codes_fin, const float* __restrict__ xhat_fin,
    float* __restrict__ out)
{
  int b = blockIdx.x, lane = threadIdx.x;
  float2 t = *(const float2*)(xhat_fin + (size_t)(b * BEAMW) * DD + lane * 2);
  *(float2*)(out + (size_t)MM * BB + (size_t)b * DD + lane * 2) = t;
  if (lane < MM) out[lane * BB + b] = (float)codes_fin[(b * BEAMW) * MM + lane];
}

extern "C" void kernel_launch(void* const* d_in, const int* in_sizes, int n_in,
                              void* d_out, int out_size, void* d_ws, size_t ws_size,
                              hipStream_t stream)
{
  (void)in_sizes; (void)n_in; (void)out_size; (void)ws_size;
  const float* x    = (const float*)d_in[0];
  const float* cb   = (const float*)d_in[1];
  const float* rq   = (const float*)d_in[2];
  const float* Win  = (const float*)d_in[3];
  const float* bin  = (const float*)d_in[4];
  const float* Wcat = (const float*)d_in[5];
  const float* bcat = (const float*)d_in[6];
  const float* W1   = (const float*)d_in[7];
  const float* b1   = (const float*)d_in[8];
  const float* W2   = (const float*)d_in[9];
  const float* b2   = (const float*)d_in[10];
  const float* Wout = (const float*)d_in[11];
  const float* bout = (const float*)d_in[12];
  float* out = (float*)d_out;

  char* ws = (char*)d_ws;
  size_t off = 0;
  auto alloc = [&](size_t bytes) -> void* {
    void* p = ws + off;
    off += (bytes + 255) & ~(size_t)255;
    return p;
  };
  float* X0    = (float*)alloc((size_t)BB * BEAMW * DD * 4);
  float* X1    = (float*)alloc((size_t)BB * BEAMW * DD * 4);
  int*   C0    = (int*)  alloc((size_t)BB * BEAMW * MM * 4);
  int*   C1    = (int*)  alloc((size_t)BB * BEAMW * MM * 4);
  int*   tc    = (int*)  alloc((size_t)BB * BEAMW * AA * 4);
  float* d2b   = (float*)alloc((size_t)BB * 128 * 4);
  float* candb = (float*)alloc((size_t)BB * 128 * DD * 4);
  float* xtg   = (float*)alloc((size_t)BB * BEAMW * 256 * 4);
  float* rqT7  = (float*)alloc((size_t)SS * DD * KK * 4);
  float* rqn7  = (float*)alloc((size_t)SS * KK * 4);
  float* ct7   = (float*)alloc((size_t)SS * KK * HH * 4);
  _Float16* wAh7 = (_Float16*)alloc((size_t)SS * 4 * 65536 * 2);
  _Float16* wAl7 = (_Float16*)alloc((size_t)SS * 4 * 65536 * 2);
  _Float16* woh7 = (_Float16*)alloc((size_t)SS * 32768 * 2);
  _Float16* wol7 = (_Float16*)alloc((size_t)SS * 32768 * 2);
  _Float16* wch7 = (_Float16*)alloc((size_t)SS * 32768 * 2);
  _Float16* wcl7 = (_Float16*)alloc((size_t)SS * 32768 * 2);

  // step-independent prep for ALL steps, upfront
  wpack_kernel<<<(SS * 40960) / 256, 256, 0, stream>>>(
      W1, W2, Wout, Wcat, wAh7, wAl7, woh7, wol7, wch7, wcl7);
  rqprep_kernel<<<SS * KK, DD, 0, stream>>>(rq, rqT7, rqn7);
  codeterm_kernel<<<SS * KK, HH, 0, stream>>>(cb, Win, bin, Wcat, bcat, ct7);

  step0_kernel<<<BB, 64, 0, stream>>>(x, cb, X0, C0);
  float* Xc = X0; float* Xn = X1;
  int* Cc = C0; int* Cn = C1;
  for (int s = 0; s < SS; ++s) {
    prefilter_kernel<<<(BB * BEAMW) / 32, 256, 0, stream>>>(
        x, Xc, rqT7 + (size_t)s * DD * KK, rqn7 + (size_t)s * KK, tc);
    xterm_kernel<<<(BB * BEAMW) / 16, 256, 0, stream>>>(
        Xc, wch7 + (size_t)s * 32768, wcl7 + (size_t)s * 32768, xtg);
    mlp_kernel<<<(BB * BEAMW * AA) / WM, 1024, 0, stream>>>(
        x, Xc, tc, ct7 + (size_t)s * KK * HH,
        cb + (size_t)(s + 1) * KK * DD, xtg,
        wAh7 + (size_t)s * 262144, wAl7 + (size_t)s * 262144,
        woh7 + (size_t)s * 32768, wol7 + (size_t)s * 32768,
        b1 + (size_t)s * 2 * HH, b2 + (size_t)s * 2 * HH,
        bout + (size_t)s * DD,
        candb, d2b);
    int fo = (s < SS - 1) ? BEAMW : 1;
    topk_update_kernel<<<BB, 64, 0, stream>>>(d2b, candb, Cc, tc, Xn, Cn, fo, s + 1);
    { float* t = Xc; Xc = Xn; Xn = t; }
    { int* t = Cc; Cc = Cn; Cn = t; }
  }
  finalize_kernel<<<BB, 64, 0, stream>>>(Cc, Xc, out);
}

// Round 16
// 4676.212 us; speedup vs baseline: 1.2866x; 1.2866x over previous
//
#include <hip/hip_runtime.h>
#include <float.h>

#define BB    2048
#define DD    128
#define KK    256
#define HH    256
#define MM    8
#define SS    7
#define BEAMW 16
#define AA    8
#define WM    64   // candidates per mlp block

typedef _Float16 f16x8 __attribute__((ext_vector_type(8)));
typedef float    f32x4 __attribute__((ext_vector_type(4)));

// swizzled index into a [rows][32] fp32 LDS tile (prefilter only)
#define HSWZ(row, m) (((row) << 5) + ((((m) + ((((row) >> 3)) << 2))) & 31))

// halfword offset into a [WM][256] f16 LDS tile, 8-halfword blocks XOR-swizzled
__device__ __forceinline__ int hoff(int m, int j) {
  return m * 256 + ((((j >> 3) ^ (m & 7)) << 3) | (j & 7));
}

// ---------------------------------------------------------------- step 0
__global__ __launch_bounds__(64) void step0_kernel(
    const float* __restrict__ x, const float* __restrict__ cb,
    float* __restrict__ xhat, int* __restrict__ codes)
{
  int b = blockIdx.x, l = threadIdx.x;
  __shared__ float xs[DD];
  xs[l]      = x[b * DD + l];
  xs[l + 64] = x[b * DD + 64 + l];
  __syncthreads();
  float dist[4];
#pragma unroll
  for (int q = 0; q < 4; ++q) {
    const float* row = cb + (size_t)(q * 64 + l) * DD;
    float dot = 0.f, nrm = 0.f;
#pragma unroll 8
    for (int d = 0; d < DD; d += 4) {
      float4 c = *(const float4*)(row + d);
      dot += c.x * xs[d] + c.y * xs[d + 1] + c.z * xs[d + 2] + c.w * xs[d + 3];
      nrm += c.x * c.x + c.y * c.y + c.z * c.z + c.w * c.w;
    }
    dist[q] = nrm - 2.f * dot;
  }
  for (int it = 0; it < BEAMW; ++it) {
    float bv = dist[0]; int bi = l;
#pragma unroll
    for (int q = 1; q < 4; ++q) {
      if (dist[q] < bv) { bv = dist[q]; bi = q * 64 + l; }
    }
#pragma unroll
    for (int mmk = 1; mmk < 64; mmk <<= 1) {
      float ov = __shfl_xor(bv, mmk);
      int   oi = __shfl_xor(bi, mmk);
      if (ov < bv || (ov == bv && oi < bi)) { bv = ov; bi = oi; }
    }
    const float* crow = cb + (size_t)bi * DD;
    float2 v = *(const float2*)(crow + l * 2);
    *(float2*)(xhat + (size_t)(b * BEAMW + it) * DD + l * 2) = v;
    if (l == 0) codes[(b * BEAMW + it) * MM] = bi;
    if (l == (bi & 63)) dist[bi >> 6] = FLT_MAX;
  }
}

// --------------------- upfront: rq^T + norms for ALL steps
__global__ __launch_bounds__(128) void rqprep_kernel(
    const float* __restrict__ rq, float* __restrict__ rqT7, float* __restrict__ rqn7)
{
  int s = blockIdx.x >> 8, k = blockIdx.x & 255, d = threadIdx.x;
  float v = rq[(size_t)s * KK * DD + k * DD + d];
  rqT7[(size_t)s * DD * KK + d * KK + k] = v;
  float p = v * v;
#pragma unroll
  for (int mmk = 1; mmk < 64; mmk <<= 1) p += __shfl_xor(p, mmk);
  __shared__ float ps[2];
  if ((d & 63) == 0) ps[d >> 6] = p;
  __syncthreads();
  if (d == 0) rqn7[s * KK + k] = ps[0] + ps[1];
}

// --------------------- upfront: per-code linear-path table for ALL steps
__global__ __launch_bounds__(256) void codeterm_kernel(
    const float* __restrict__ cb, const float* __restrict__ Win,
    const float* __restrict__ bin, const float* __restrict__ Wcat,
    const float* __restrict__ bcat, float* __restrict__ ct7)
{
  int s = blockIdx.x >> 8, k = blockIdx.x & 255, j = threadIdx.x;
  const float* cbstep = cb + (size_t)(s + 1) * KK * DD;
  const float* WinS   = Win + (size_t)s * DD * HH;
  const float* WcatS  = Wcat + (size_t)s * 384 * HH;
  __shared__ float crow[DD];
  __shared__ float h1[HH];
  if (j < DD) crow[j] = cbstep[k * DD + j];
  __syncthreads();
  float a = bin[s * HH + j];
  for (int d = 0; d < DD; ++d) a += crow[d] * WinS[d * HH + j];
  h1[j] = a;
  __syncthreads();
  float c = bcat[s * HH + j];
  for (int t = 0; t < HH; ++t) c += h1[t] * WcatS[t * HH + j];
  ct7[(size_t)s * KK * HH + k * HH + j] = c;
}

// --------------------- upfront: pack weights (hi/lo f16 frags) for ALL steps
__global__ __launch_bounds__(256) void wpack_kernel(
    const float* __restrict__ W1, const float* __restrict__ W2,
    const float* __restrict__ Wout, const float* __restrict__ Wcat,
    _Float16* __restrict__ wAh7, _Float16* __restrict__ wAl7,
    _Float16* __restrict__ woh7, _Float16* __restrict__ wol7,
    _Float16* __restrict__ wch7, _Float16* __restrict__ wcl7)
{
  int tg = blockIdx.x * 256 + threadIdx.x;
  int s = tg / 40960;
  int t = tg % 40960;
  const float* src; _Float16 *dh, *dl;
  int N, r;
  if (t < 32768) {
    int mi = t >> 13; r = t & 8191;
    src = (mi & 1 ? W2 : W1) + (size_t)s * 2 * HH * HH + (size_t)(mi >> 1) * HH * HH;
    dh = wAh7 + (size_t)s * 262144 + (size_t)mi * 65536;
    dl = wAl7 + (size_t)s * 262144 + (size_t)mi * 65536;
    N = 256;
  } else if (t < 36864) {
    r = t - 32768;
    src = Wout + (size_t)s * HH * DD;
    dh = woh7 + (size_t)s * 32768; dl = wol7 + (size_t)s * 32768;
    N = 128;
  } else {
    r = t - 36864;
    src = Wcat + (size_t)s * 384 * HH + (size_t)256 * HH;
    dh = wch7 + (size_t)s * 32768; dl = wcl7 + (size_t)s * 32768;
    N = 256;
  }
  int l = r & 63;
  int nct = N >> 4;
  int c = (r >> 6) & (nct - 1);
  int q = r / (64 * nct);
  int k0 = q * 32 + (l >> 4) * 8;
  int col = c * 16 + (l & 15);
  size_t fo = (size_t)r * 8;
#pragma unroll
  for (int j = 0; j < 8; ++j) {
    float v = src[(size_t)(k0 + j) * N + col];
    _Float16 hi = (_Float16)v;
    dh[fo + j] = hi;
    dl[fo + j] = (_Float16)((v - (float)hi) * 2048.0f);
  }
}

// ------------- per-step: xterm = xhat @ Wcat2 -> xtg[32768][256] (f32)
__global__ __launch_bounds__(256) void xterm_kernel(
    const float* __restrict__ xhat,
    const _Float16* __restrict__ wch, const _Float16* __restrict__ wcl,
    float* __restrict__ xtg)
{
  int tid = threadIdx.x;
  int l = tid & 63, w = tid >> 6;
  int lg = l >> 4, lr = l & 15;
  int r0 = blockIdx.x * 16;
  const f32x4 z4 = {0.f, 0.f, 0.f, 0.f};
  f32x4 a1[4], a2[4];
#pragma unroll
  for (int c = 0; c < 4; ++c) { a1[c] = z4; a2[c] = z4; }
  for (int q = 0; q < 4; ++q) {
    const float* ap = xhat + (size_t)(r0 + lr) * DD + q * 32 + lg * 8;
    float4 f0 = *(const float4*)ap;
    float4 f1 = *(const float4*)(ap + 4);
    float fv[8] = {f0.x, f0.y, f0.z, f0.w, f1.x, f1.y, f1.z, f1.w};
    f16x8 Ah, Al;
#pragma unroll
    for (int j = 0; j < 8; ++j) {
      _Float16 hi = (_Float16)fv[j];
      Ah[j] = hi;
      Al[j] = (_Float16)((fv[j] - (float)hi) * 2048.0f);
    }
#pragma unroll
    for (int c = 0; c < 4; ++c) {
      size_t boff = ((size_t)(q * 16 + w * 4 + c) * 64 + l) * 8;
      f16x8 Bh = *(const f16x8*)&wch[boff];
      f16x8 Bl = *(const f16x8*)&wcl[boff];
      a1[c] = __builtin_amdgcn_mfma_f32_16x16x32_f16(Ah, Bh, a1[c], 0, 0, 0);
      a2[c] = __builtin_amdgcn_mfma_f32_16x16x32_f16(Al, Bh, a2[c], 0, 0, 0);
      a2[c] = __builtin_amdgcn_mfma_f32_16x16x32_f16(Ah, Bl, a2[c], 0, 0, 0);
    }
  }
#pragma unroll
  for (int c = 0; c < 4; ++c) {
    int col = (w * 4 + c) * 16 + lr;
#pragma unroll
    for (int r = 0; r < 4; ++r) {
      int row = r0 + lg * 4 + r;
      xtg[(size_t)row * 256 + col] = a1[c][r] + a2[c][r] * (1.0f / 2048.0f);
    }
  }
}

// --------------------- per-step: distance prefilter + top-8 per (b,f)
__global__ __launch_bounds__(256) void prefilter_kernel(
    const float* __restrict__ x, const float* __restrict__ xhat,
    const float* __restrict__ rqT, const float* __restrict__ rqn,
    int* __restrict__ topc)
{
  __shared__ float xtT[DD * 32];
  __shared__ float distb[32 * KK];
  int tid = threadIdx.x;
  int bf0 = blockIdx.x * 32;
  for (int i = 0; i < 16; ++i) {
    int idx = tid + i * 256;
    int d = idx >> 5, r = idx & 31;
    int bf = bf0 + r;
    xtT[HSWZ(d, r)] = x[(bf >> 4) * DD + d] - xhat[(size_t)bf * DD + d];
  }
  __syncthreads();
  int jb = tid & 31, mb = tid >> 5;
  float acc[4][8];
#pragma unroll
  for (int i = 0; i < 4; ++i)
#pragma unroll
    for (int jj = 0; jj < 8; ++jj) acc[i][jj] = 0.f;
  for (int d = 0; d < DD; ++d) {
    float4 hv = *(float4*)&xtT[HSWZ(d, mb * 4)];
    float4 w0 = *(const float4*)&rqT[d * KK + jb * 8];
    float4 w1 = *(const float4*)&rqT[d * KK + jb * 8 + 4];
    float hvv[4] = {hv.x, hv.y, hv.z, hv.w};
    float wv[8]  = {w0.x, w0.y, w0.z, w0.w, w1.x, w1.y, w1.z, w1.w};
#pragma unroll
    for (int i = 0; i < 4; ++i)
#pragma unroll
      for (int jj = 0; jj < 8; ++jj) acc[i][jj] += hvv[i] * wv[jj];
  }
#pragma unroll
  for (int i = 0; i < 4; ++i) {
    int r = mb * 4 + i;
#pragma unroll
    for (int jj = 0; jj < 8; ++jj) {
      int k = jb * 8 + jj;
      distb[r * KK + k] = rqn[k] - 2.f * acc[i][jj];
    }
  }
  __syncthreads();
  int wv2 = tid >> 6, lane = tid & 63;
  for (int rr = 0; rr < 8; ++rr) {
    int r = wv2 * 8 + rr;
    float v[4];
#pragma unroll
    for (int q = 0; q < 4; ++q) v[q] = distb[r * KK + lane + q * 64];
    int bfr = bf0 + r;
    for (int it = 0; it < AA; ++it) {
      float bv = v[0]; int bi = lane;
#pragma unroll
      for (int q = 1; q < 4; ++q) {
        if (v[q] < bv) { bv = v[q]; bi = q * 64 + lane; }
      }
#pragma unroll
      for (int mmk = 1; mmk < 64; mmk <<= 1) {
        float ov = __shfl_xor(bv, mmk);
        int   oi = __shfl_xor(bi, mmk);
        if (ov < bv || (ov == bv && oi < bi)) { bv = ov; bi = oi; }
      }
      if (lane == (bi & 63)) v[bi >> 6] = FLT_MAX;
      if (lane == 0) topc[bfr * AA + it] = bi;
    }
  }
}

// ----------------------- per-step: fused residual MLP via split-f16 MFMA
// 64 candidates / 1024-thread block (16 waves, wave w owns coltile w).
// Separate u buffer -> 2 barriers/layer. GEMM2's residual acc-init reads the
// thread's OWN h slots from LDS (no cross-thread hazard, no extra registers).
__global__ __launch_bounds__(1024, 4) void mlp_kernel(
    const float* __restrict__ x, const float* __restrict__ xhat,
    const int* __restrict__ topc, const float* __restrict__ ct,
    const float* __restrict__ cbstep, const float* __restrict__ xtg,
    const _Float16* __restrict__ wAh, const _Float16* __restrict__ wAl,
    const _Float16* __restrict__ woh, const _Float16* __restrict__ wol,
    const float* __restrict__ b1a, const float* __restrict__ b2a,
    const float* __restrict__ bout,
    float* __restrict__ cand, float* __restrict__ d2g)
{
  __shared__ _Float16 hhi[WM * 256], hlo[WM * 256];   // 64 KB  h
  __shared__ _Float16 uhi[WM * 256], ulo[WM * 256];   // 64 KB  u
  __shared__ float xs[DD];
  __shared__ float pd2[WM][8];
  __shared__ int   cl[WM];

  int tid = threadIdx.x;
  int l = tid & 63, w = tid >> 6;          // w in [0,16)
  int lg = l >> 4, lr = l & 15;
  int bf0 = blockIdx.x * 8;               // 8 beam elems per block
  int b = bf0 >> 4;
  const f32x4 z4 = {0.f, 0.f, 0.f, 0.f};

  if (tid < WM) cl[tid] = topc[bf0 * AA + tid];
  if (tid < DD) xs[tid] = x[b * DD + tid];
  __syncthreads();

  // column ownership: wave w -> coltile w of N=256
  int j0 = w * 16 + lr;

  // ---- h_init own slots: ct[cl[m]][j0] + xtg[...][j0]
#pragma unroll
  for (int rt = 0; rt < 4; ++rt)
#pragma unroll
    for (int r = 0; r < 4; ++r) {
      int m = rt * 16 + lg * 4 + r;
      float v = ct[cl[m] * HH + j0] + xtg[(size_t)(bf0 + (m >> 3)) * 256 + j0];
      _Float16 hi = (_Float16)v;
      int off = hoff(m, j0);
      hhi[off] = hi;
      hlo[off] = (_Float16)((v - (float)hi) * 2048.0f);
    }
  __syncthreads();   // h visible

  // ---- residual layers
  for (int lay = 0; lay < 2; ++lay) {
    const _Float16* W1h = wAh + (size_t)(lay * 2 + 0) * 65536;
    const _Float16* W1l = wAl + (size_t)(lay * 2 + 0) * 65536;
    const _Float16* W2h = wAh + (size_t)(lay * 2 + 1) * 65536;
    const _Float16* W2l = wAl + (size_t)(lay * 2 + 1) * 65536;

    // GEMM1: u = relu(h @ W1 + b1)
    f32x4 a1[4], a2[4];
#pragma unroll
    for (int rt = 0; rt < 4; ++rt) { a1[rt] = z4; a2[rt] = z4; }
    for (int q = 0; q < 8; ++q) {
      size_t boff = ((size_t)(q * 16 + w) * 64 + l) * 8;
      f16x8 Bh = *(const f16x8*)&W1h[boff];
      f16x8 Bl = *(const f16x8*)&W1l[boff];
#pragma unroll
      for (int rt = 0; rt < 4; ++rt) {
        int arow = rt * 16 + lr;
        int aoff = arow * 256 + (((q * 4 + lg) ^ (arow & 7)) << 3);
        f16x8 Ah = *(f16x8*)&hhi[aoff];
        f16x8 Al = *(f16x8*)&hlo[aoff];
        a1[rt] = __builtin_amdgcn_mfma_f32_16x16x32_f16(Ah, Bh, a1[rt], 0, 0, 0);
        a2[rt] = __builtin_amdgcn_mfma_f32_16x16x32_f16(Al, Bh, a2[rt], 0, 0, 0);
        a2[rt] = __builtin_amdgcn_mfma_f32_16x16x32_f16(Ah, Bl, a2[rt], 0, 0, 0);
      }
    }
    // epilogue: write u into the SEPARATE u buffer
    {
      float bj = b1a[lay * HH + j0];
#pragma unroll
      for (int rt = 0; rt < 4; ++rt)
#pragma unroll
        for (int r = 0; r < 4; ++r) {
          int m = rt * 16 + lg * 4 + r;
          float u = fmaxf(a1[rt][r] + a2[rt][r] * (1.0f / 2048.0f) + bj, 0.f);
          _Float16 hi = (_Float16)u;
          int off = hoff(m, j0);
          uhi[off] = hi;
          ulo[off] = (_Float16)((u - (float)hi) * 2048.0f);
        }
    }
    __syncthreads();   // u visible; all GEMM1 h-reads done

    // GEMM2: h' = res + u @ W2 + b2; res read from OWN h slots into acc
#pragma unroll
    for (int rt = 0; rt < 4; ++rt) {
#pragma unroll
      for (int r = 0; r < 4; ++r) {
        int m = rt * 16 + lg * 4 + r;
        int off = hoff(m, j0);
        a1[rt][r] = (float)hhi[off] + (float)hlo[off] * (1.0f / 2048.0f);
      }
      a2[rt] = z4;
    }
    for (int q = 0; q < 8; ++q) {
      size_t boff = ((size_t)(q * 16 + w) * 64 + l) * 8;
      f16x8 Bh = *(const f16x8*)&W2h[boff];
      f16x8 Bl = *(const f16x8*)&W2l[boff];
#pragma unroll
      for (int rt = 0; rt < 4; ++rt) {
        int arow = rt * 16 + lr;
        int aoff = arow * 256 + (((q * 4 + lg) ^ (arow & 7)) << 3);
        f16x8 Ah = *(f16x8*)&uhi[aoff];
        f16x8 Al = *(f16x8*)&ulo[aoff];
        a1[rt] = __builtin_amdgcn_mfma_f32_16x16x32_f16(Ah, Bh, a1[rt], 0, 0, 0);
        a2[rt] = __builtin_amdgcn_mfma_f32_16x16x32_f16(Al, Bh, a2[rt], 0, 0, 0);
        a2[rt] = __builtin_amdgcn_mfma_f32_16x16x32_f16(Ah, Bl, a2[rt], 0, 0, 0);
      }
    }
    // epilogue: h' back into h buffer (own slots; no one reads h in GEMM2)
    {
      float bj = b2a[lay * HH + j0];
#pragma unroll
      for (int rt = 0; rt < 4; ++rt)
#pragma unroll
        for (int r = 0; r < 4; ++r) {
          int m = rt * 16 + lg * 4 + r;
          float v = a1[rt][r] + a2[rt][r] * (1.0f / 2048.0f) + bj;
          _Float16 hi = (_Float16)v;
          int off = hoff(m, j0);
          hhi[off] = hi;
          hlo[off] = (_Float16)((v - (float)hi) * 2048.0f);
        }
    }
    __syncthreads();   // h' visible
  }

  // ---- out stage: cand = h @ W_out + b_out + cw_res + xhat; d2 scoring
  // N=128 -> coltile c8 = w&7; row-half mh = w>>3 covers rts {2mh, 2mh+1}
  int c8 = w & 7, mh = w >> 3;
  f32x4 o1[2], o2[2];
  o1[0] = z4; o1[1] = z4; o2[0] = z4; o2[1] = z4;
  for (int q = 0; q < 8; ++q) {
    size_t boff = ((size_t)(q * 8 + c8) * 64 + l) * 8;
    f16x8 Bh = *(const f16x8*)&woh[boff];
    f16x8 Bl = *(const f16x8*)&wol[boff];
#pragma unroll
    for (int rr = 0; rr < 2; ++rr) {
      int arow = (mh * 2 + rr) * 16 + lr;
      int aoff = arow * 256 + (((q * 4 + lg) ^ (arow & 7)) << 3);
      f16x8 Ah = *(f16x8*)&hhi[aoff];
      f16x8 Al = *(f16x8*)&hlo[aoff];
      o1[rr] = __builtin_amdgcn_mfma_f32_16x16x32_f16(Ah, Bh, o1[rr], 0, 0, 0);
      o2[rr] = __builtin_amdgcn_mfma_f32_16x16x32_f16(Al, Bh, o2[rr], 0, 0, 0);
      o2[rr] = __builtin_amdgcn_mfma_f32_16x16x32_f16(Ah, Bl, o2[rr], 0, 0, 0);
    }
  }
  int ci0 = (blockIdx.x & 1) * WM;
  int d = c8 * 16 + lr;
  float bo = bout[d];
  float xsd = xs[d];
#pragma unroll
  for (int rr = 0; rr < 2; ++rr) {
    int rt = mh * 2 + rr;
    float p[4];
#pragma unroll
    for (int r = 0; r < 4; ++r) {
      int m = rt * 16 + lg * 4 + r;
      float v = o1[rr][r] + o2[rr][r] * (1.0f / 2048.0f) + bo
              + cbstep[(size_t)cl[m] * DD + d]
              + xhat[(size_t)(bf0 + (m >> 3)) * DD + d];
      cand[((size_t)(b * 128 + ci0 + m)) * DD + d] = v;
      p[r] = v * (v - 2.f * xsd);
    }
#pragma unroll
    for (int mk = 1; mk < 16; mk <<= 1) {
#pragma unroll
      for (int r = 0; r < 4; ++r) p[r] += __shfl_xor(p[r], mk);
    }
    if (lr == 0) {
#pragma unroll
      for (int r = 0; r < 4; ++r) pd2[rt * 16 + lg * 4 + r][c8] = p[r];
    }
  }
  __syncthreads();
  if (tid < WM) {
    float s = 0.f;
#pragma unroll
    for (int ww = 0; ww < 8; ++ww) s += pd2[tid][ww];
    d2g[b * 128 + ci0 + tid] = s;
  }
}

// --------------------------- per-step: top-F_out prune + gather update
__global__ __launch_bounds__(64) void topk_update_kernel(
    const float* __restrict__ d2g, const float* __restrict__ cand,
    const int* __restrict__ codes_in, const int* __restrict__ topc,
    float* __restrict__ xhat_out, int* __restrict__ codes_out,
    int fout, int spos)
{
  int b = blockIdx.x, lane = threadIdx.x;
  float v0 = d2g[b * 128 + lane];
  float v1 = d2g[b * 128 + 64 + lane];
  for (int r = 0; r < fout; ++r) {
    float bv = v0; int bi = lane;
    if (v1 < bv) { bv = v1; bi = 64 + lane; }
#pragma unroll
    for (int mmk = 1; mmk < 64; mmk <<= 1) {
      float ov = __shfl_xor(bv, mmk);
      int   oi = __shfl_xor(bi, mmk);
      if (ov < bv || (ov == bv && oi < bi)) { bv = ov; bi = oi; }
    }
    int parent = bi >> 3, a = bi & 7;
    if (lane < MM) {
      int valc = (lane == spos) ? topc[(b * BEAMW + parent) * AA + a]
                                : codes_in[(b * BEAMW + parent) * MM + lane];
      codes_out[(b * BEAMW + r) * MM + lane] = valc;
    }
    const float* src = cand + ((size_t)(b * 128 + bi)) * DD;
    float2 t = *(const float2*)(src + lane * 2);
    *(float2*)(xhat_out + (size_t)(b * BEAMW + r) * DD + lane * 2) = t;
    if (bi < 64) { if (lane == bi) v0 = FLT_MAX; }
    else         { if (lane == bi - 64) v1 = FLT_MAX; }
  }
}

// ---------------------------------------------------------------- output
__global__ __launch_bounds__(64) void finalize_kernel(
    const int* __restrict__ codes_fin, const float* __restrict__ xhat_fin,
    float* __restrict__ out)
{
  int b = blockIdx.x, lane = threadIdx.x;
  float2 t = *(const float2*)(xhat_fin + (size_t)(b * BEAMW) * DD + lane * 2);
  *(float2*)(out + (size_t)MM * BB + (size_t)b * DD + lane * 2) = t;
  if (lane < MM) out[lane * BB + b] = (float)codes_fin[(b * BEAMW) * MM + lane];
}

extern "C" void kernel_launch(void* const* d_in, const int* in_sizes, int n_in,
                              void* d_out, int out_size, void* d_ws, size_t ws_size,
                              hipStream_t stream)
{
  (void)in_sizes; (void)n_in; (void)out_size; (void)ws_size;
  const float* x    = (const float*)d_in[0];
  const float* cb   = (const float*)d_in[1];
  const float* rq   = (const float*)d_in[2];
  const float* Win  = (const float*)d_in[3];
  const float* bin  = (const float*)d_in[4];
  const float* Wcat = (const float*)d_in[5];
  const float* bcat = (const float*)d_in[6];
  const float* W1   = (const float*)d_in[7];
  const float* b1   = (const float*)d_in[8];
  const float* W2   = (const float*)d_in[9];
  const float* b2   = (const float*)d_in[10];
  const float* Wout = (const float*)d_in[11];
  const float* bout = (const float*)d_in[12];
  float* out = (float*)d_out;

  char* ws = (char*)d_ws;
  size_t off = 0;
  auto alloc = [&](size_t bytes) -> void* {
    void* p = ws + off;
    off += (bytes + 255) & ~(size_t)255;
    return p;
  };
  float* X0    = (float*)alloc((size_t)BB * BEAMW * DD * 4);
  float* X1    = (float*)alloc((size_t)BB * BEAMW * DD * 4);
  int*   C0    = (int*)  alloc((size_t)BB * BEAMW * MM * 4);
  int*   C1    = (int*)  alloc((size_t)BB * BEAMW * MM * 4);
  int*   tc    = (int*)  alloc((size_t)BB * BEAMW * AA * 4);
  float* d2b   = (float*)alloc((size_t)BB * 128 * 4);
  float* candb = (float*)alloc((size_t)BB * 128 * DD * 4);
  float* xtg   = (float*)alloc((size_t)BB * BEAMW * 256 * 4);
  float* rqT7  = (float*)alloc((size_t)SS * DD * KK * 4);
  float* rqn7  = (float*)alloc((size_t)SS * KK * 4);
  float* ct7   = (float*)alloc((size_t)SS * KK * HH * 4);
  _Float16* wAh7 = (_Float16*)alloc((size_t)SS * 4 * 65536 * 2);
  _Float16* wAl7 = (_Float16*)alloc((size_t)SS * 4 * 65536 * 2);
  _Float16* woh7 = (_Float16*)alloc((size_t)SS * 32768 * 2);
  _Float16* wol7 = (_Float16*)alloc((size_t)SS * 32768 * 2);
  _Float16* wch7 = (_Float16*)alloc((size_t)SS * 32768 * 2);
  _Float16* wcl7 = (_Float16*)alloc((size_t)SS * 32768 * 2);

  // step-independent prep for ALL steps, upfront
  wpack_kernel<<<(SS * 40960) / 256, 256, 0, stream>>>(
      W1, W2, Wout, Wcat, wAh7, wAl7, woh7, wol7, wch7, wcl7);
  rqprep_kernel<<<SS * KK, DD, 0, stream>>>(rq, rqT7, rqn7);
  codeterm_kernel<<<SS * KK, HH, 0, stream>>>(cb, Win, bin, Wcat, bcat, ct7);

  step0_kernel<<<BB, 64, 0, stream>>>(x, cb, X0, C0);
  float* Xc = X0; float* Xn = X1;
  int* Cc = C0; int* Cn = C1;
  for (int s = 0; s < SS; ++s) {
    prefilter_kernel<<<(BB * BEAMW) / 32, 256, 0, stream>>>(
        x, Xc, rqT7 + (size_t)s * DD * KK, rqn7 + (size_t)s * KK, tc);
    xterm_kernel<<<(BB * BEAMW) / 16, 256, 0, stream>>>(
        Xc, wch7 + (size_t)s * 32768, wcl7 + (size_t)s * 32768, xtg);
    mlp_kernel<<<(BB * BEAMW * AA) / WM, 1024, 0, stream>>>(
        x, Xc, tc, ct7 + (size_t)s * KK * HH,
        cb + (size_t)(s + 1) * KK * DD, xtg,
        wAh7 + (size_t)s * 262144, wAl7 + (size_t)s * 262144,
        woh7 + (size_t)s * 32768, wol7 + (size_t)s * 32768,
        b1 + (size_t)s * 2 * HH, b2 + (size_t)s * 2 * HH,
        bout + (size_t)s * DD,
        candb, d2b);
    int fo = (s < SS - 1) ? BEAMW : 1;
    topk_update_kernel<<<BB, 64, 0, stream>>>(d2b, candb, Cc, tc, Xn, Cn, fo, s + 1);
    { float* t = Xc; Xc = Xn; Xn = t; }
    { int* t = Cc; Cc = Cn; Cn = t; }
  }
  finalize_kernel<<<BB, 64, 0, stream>>>(Cc, Xc, out);
}

// Round 17
// 4565.511 us; speedup vs baseline: 1.3178x; 1.0242x over previous
//
#include <hip/hip_runtime.h>
#include <float.h>

#define BB    2048
#define DD    128
#define KK    256
#define HH    256
#define MM    8
#define SS    7
#define BEAMW 16
#define AA    8
#define WM    64   // candidates per mlp block

typedef _Float16 f16x8 __attribute__((ext_vector_type(8)));
typedef float    f32x4 __attribute__((ext_vector_type(4)));

// swizzled index into a [rows][32] fp32 LDS tile (prefilter only)
#define HSWZ(row, m) (((row) << 5) + ((((m) + ((((row) >> 3)) << 2))) & 31))

// halfword offset into a [WM][256] f16 LDS tile, 8-halfword blocks XOR-swizzled
__device__ __forceinline__ int hoff(int m, int j) {
  return m * 256 + ((((j >> 3) ^ (m & 7)) << 3) | (j & 7));
}

// ---------------------------------------------------------------- step 0
__global__ __launch_bounds__(64) void step0_kernel(
    const float* __restrict__ x, const float* __restrict__ cb,
    float* __restrict__ xhat, int* __restrict__ codes)
{
  int b = blockIdx.x, l = threadIdx.x;
  __shared__ float xs[DD];
  xs[l]      = x[b * DD + l];
  xs[l + 64] = x[b * DD + 64 + l];
  __syncthreads();
  float dist[4];
#pragma unroll
  for (int q = 0; q < 4; ++q) {
    const float* row = cb + (size_t)(q * 64 + l) * DD;
    float dot = 0.f, nrm = 0.f;
#pragma unroll 8
    for (int d = 0; d < DD; d += 4) {
      float4 c = *(const float4*)(row + d);
      dot += c.x * xs[d] + c.y * xs[d + 1] + c.z * xs[d + 2] + c.w * xs[d + 3];
      nrm += c.x * c.x + c.y * c.y + c.z * c.z + c.w * c.w;
    }
    dist[q] = nrm - 2.f * dot;
  }
  for (int it = 0; it < BEAMW; ++it) {
    float bv = dist[0]; int bi = l;
#pragma unroll
    for (int q = 1; q < 4; ++q) {
      if (dist[q] < bv) { bv = dist[q]; bi = q * 64 + l; }
    }
#pragma unroll
    for (int mmk = 1; mmk < 64; mmk <<= 1) {
      float ov = __shfl_xor(bv, mmk);
      int   oi = __shfl_xor(bi, mmk);
      if (ov < bv || (ov == bv && oi < bi)) { bv = ov; bi = oi; }
    }
    const float* crow = cb + (size_t)bi * DD;
    float2 v = *(const float2*)(crow + l * 2);
    *(float2*)(xhat + (size_t)(b * BEAMW + it) * DD + l * 2) = v;
    if (l == 0) codes[(b * BEAMW + it) * MM] = bi;
    if (l == (bi & 63)) dist[bi >> 6] = FLT_MAX;
  }
}

// --------------------- upfront: rq^T + norms for ALL steps
__global__ __launch_bounds__(128) void rqprep_kernel(
    const float* __restrict__ rq, float* __restrict__ rqT7, float* __restrict__ rqn7)
{
  int s = blockIdx.x >> 8, k = blockIdx.x & 255, d = threadIdx.x;
  float v = rq[(size_t)s * KK * DD + k * DD + d];
  rqT7[(size_t)s * DD * KK + d * KK + k] = v;
  float p = v * v;
#pragma unroll
  for (int mmk = 1; mmk < 64; mmk <<= 1) p += __shfl_xor(p, mmk);
  __shared__ float ps[2];
  if ((d & 63) == 0) ps[d >> 6] = p;
  __syncthreads();
  if (d == 0) rqn7[s * KK + k] = ps[0] + ps[1];
}

// --------------------- upfront: per-code linear-path table for ALL steps
__global__ __launch_bounds__(256) void codeterm_kernel(
    const float* __restrict__ cb, const float* __restrict__ Win,
    const float* __restrict__ bin, const float* __restrict__ Wcat,
    const float* __restrict__ bcat, float* __restrict__ ct7)
{
  int s = blockIdx.x >> 8, k = blockIdx.x & 255, j = threadIdx.x;
  const float* cbstep = cb + (size_t)(s + 1) * KK * DD;
  const float* WinS   = Win + (size_t)s * DD * HH;
  const float* WcatS  = Wcat + (size_t)s * 384 * HH;
  __shared__ float crow[DD];
  __shared__ float h1[HH];
  if (j < DD) crow[j] = cbstep[k * DD + j];
  __syncthreads();
  float a = bin[s * HH + j];
  for (int d = 0; d < DD; ++d) a += crow[d] * WinS[d * HH + j];
  h1[j] = a;
  __syncthreads();
  float c = bcat[s * HH + j];
  for (int t = 0; t < HH; ++t) c += h1[t] * WcatS[t * HH + j];
  ct7[(size_t)s * KK * HH + k * HH + j] = c;
}

// --------------------- upfront: pack weights (hi/lo f16 frags) for ALL steps
__global__ __launch_bounds__(256) void wpack_kernel(
    const float* __restrict__ W1, const float* __restrict__ W2,
    const float* __restrict__ Wout, const float* __restrict__ Wcat,
    _Float16* __restrict__ wAh7, _Float16* __restrict__ wAl7,
    _Float16* __restrict__ woh7, _Float16* __restrict__ wol7,
    _Float16* __restrict__ wch7, _Float16* __restrict__ wcl7)
{
  int tg = blockIdx.x * 256 + threadIdx.x;
  int s = tg / 40960;
  int t = tg % 40960;
  const float* src; _Float16 *dh, *dl;
  int N, r;
  if (t < 32768) {
    int mi = t >> 13; r = t & 8191;
    src = (mi & 1 ? W2 : W1) + (size_t)s * 2 * HH * HH + (size_t)(mi >> 1) * HH * HH;
    dh = wAh7 + (size_t)s * 262144 + (size_t)mi * 65536;
    dl = wAl7 + (size_t)s * 262144 + (size_t)mi * 65536;
    N = 256;
  } else if (t < 36864) {
    r = t - 32768;
    src = Wout + (size_t)s * HH * DD;
    dh = woh7 + (size_t)s * 32768; dl = wol7 + (size_t)s * 32768;
    N = 128;
  } else {
    r = t - 36864;
    src = Wcat + (size_t)s * 384 * HH + (size_t)256 * HH;
    dh = wch7 + (size_t)s * 32768; dl = wcl7 + (size_t)s * 32768;
    N = 256;
  }
  int l = r & 63;
  int nct = N >> 4;
  int c = (r >> 6) & (nct - 1);
  int q = r / (64 * nct);
  int k0 = q * 32 + (l >> 4) * 8;
  int col = c * 16 + (l & 15);
  size_t fo = (size_t)r * 8;
#pragma unroll
  for (int j = 0; j < 8; ++j) {
    float v = src[(size_t)(k0 + j) * N + col];
    _Float16 hi = (_Float16)v;
    dh[fo + j] = hi;
    dl[fo + j] = (_Float16)((v - (float)hi) * 2048.0f);
  }
}

// ------------- per-step: xterm = xhat @ Wcat2 -> xtg[32768][256] (f32)
__global__ __launch_bounds__(256) void xterm_kernel(
    const float* __restrict__ xhat,
    const _Float16* __restrict__ wch, const _Float16* __restrict__ wcl,
    float* __restrict__ xtg)
{
  int tid = threadIdx.x;
  int l = tid & 63, w = tid >> 6;
  int lg = l >> 4, lr = l & 15;
  int r0 = blockIdx.x * 16;
  const f32x4 z4 = {0.f, 0.f, 0.f, 0.f};
  f32x4 a1[4], a2[4];
#pragma unroll
  for (int c = 0; c < 4; ++c) { a1[c] = z4; a2[c] = z4; }
  for (int q = 0; q < 4; ++q) {
    const float* ap = xhat + (size_t)(r0 + lr) * DD + q * 32 + lg * 8;
    float4 f0 = *(const float4*)ap;
    float4 f1 = *(const float4*)(ap + 4);
    float fv[8] = {f0.x, f0.y, f0.z, f0.w, f1.x, f1.y, f1.z, f1.w};
    f16x8 Ah, Al;
#pragma unroll
    for (int j = 0; j < 8; ++j) {
      _Float16 hi = (_Float16)fv[j];
      Ah[j] = hi;
      Al[j] = (_Float16)((fv[j] - (float)hi) * 2048.0f);
    }
#pragma unroll
    for (int c = 0; c < 4; ++c) {
      size_t boff = ((size_t)(q * 16 + w * 4 + c) * 64 + l) * 8;
      f16x8 Bh = *(const f16x8*)&wch[boff];
      f16x8 Bl = *(const f16x8*)&wcl[boff];
      a1[c] = __builtin_amdgcn_mfma_f32_16x16x32_f16(Ah, Bh, a1[c], 0, 0, 0);
      a2[c] = __builtin_amdgcn_mfma_f32_16x16x32_f16(Al, Bh, a2[c], 0, 0, 0);
      a2[c] = __builtin_amdgcn_mfma_f32_16x16x32_f16(Ah, Bl, a2[c], 0, 0, 0);
    }
  }
#pragma unroll
  for (int c = 0; c < 4; ++c) {
    int col = (w * 4 + c) * 16 + lr;
#pragma unroll
    for (int r = 0; r < 4; ++r) {
      int row = r0 + lg * 4 + r;
      xtg[(size_t)row * 256 + col] = a1[c][r] + a2[c][r] * (1.0f / 2048.0f);
    }
  }
}

// --------------------- per-step: distance prefilter + top-8 per (b,f)
__global__ __launch_bounds__(256) void prefilter_kernel(
    const float* __restrict__ x, const float* __restrict__ xhat,
    const float* __restrict__ rqT, const float* __restrict__ rqn,
    int* __restrict__ topc)
{
  __shared__ float xtT[DD * 32];
  __shared__ float distb[32 * KK];
  int tid = threadIdx.x;
  int bf0 = blockIdx.x * 32;
  for (int i = 0; i < 16; ++i) {
    int idx = tid + i * 256;
    int d = idx >> 5, r = idx & 31;
    int bf = bf0 + r;
    xtT[HSWZ(d, r)] = x[(bf >> 4) * DD + d] - xhat[(size_t)bf * DD + d];
  }
  __syncthreads();
  int jb = tid & 31, mb = tid >> 5;
  float acc[4][8];
#pragma unroll
  for (int i = 0; i < 4; ++i)
#pragma unroll
    for (int jj = 0; jj < 8; ++jj) acc[i][jj] = 0.f;
  for (int d = 0; d < DD; ++d) {
    float4 hv = *(float4*)&xtT[HSWZ(d, mb * 4)];
    float4 w0 = *(const float4*)&rqT[d * KK + jb * 8];
    float4 w1 = *(const float4*)&rqT[d * KK + jb * 8 + 4];
    float hvv[4] = {hv.x, hv.y, hv.z, hv.w};
    float wv[8]  = {w0.x, w0.y, w0.z, w0.w, w1.x, w1.y, w1.z, w1.w};
#pragma unroll
    for (int i = 0; i < 4; ++i)
#pragma unroll
      for (int jj = 0; jj < 8; ++jj) acc[i][jj] += hvv[i] * wv[jj];
  }
#pragma unroll
  for (int i = 0; i < 4; ++i) {
    int r = mb * 4 + i;
#pragma unroll
    for (int jj = 0; jj < 8; ++jj) {
      int k = jb * 8 + jj;
      distb[r * KK + k] = rqn[k] - 2.f * acc[i][jj];
    }
  }
  __syncthreads();
  int wv2 = tid >> 6, lane = tid & 63;
  for (int rr = 0; rr < 8; ++rr) {
    int r = wv2 * 8 + rr;
    float v[4];
#pragma unroll
    for (int q = 0; q < 4; ++q) v[q] = distb[r * KK + lane + q * 64];
    int bfr = bf0 + r;
    for (int it = 0; it < AA; ++it) {
      float bv = v[0]; int bi = lane;
#pragma unroll
      for (int q = 1; q < 4; ++q) {
        if (v[q] < bv) { bv = v[q]; bi = q * 64 + lane; }
      }
#pragma unroll
      for (int mmk = 1; mmk < 64; mmk <<= 1) {
        float ov = __shfl_xor(bv, mmk);
        int   oi = __shfl_xor(bi, mmk);
        if (ov < bv || (ov == bv && oi < bi)) { bv = ov; bi = oi; }
      }
      if (lane == (bi & 63)) v[bi >> 6] = FLT_MAX;
      if (lane == 0) topc[bfr * AA + it] = bi;
    }
  }
}

// ----------------------- per-step: fused residual MLP via split-f16 MFMA
// Round-13 structure (measured best, no spill): 64 candidates / 1024 threads,
// wave w owns coltile w; in-place h/u buffer; res staged through a2 regs.
__global__ __launch_bounds__(1024, 4) void mlp_kernel(
    const float* __restrict__ x, const float* __restrict__ xhat,
    const int* __restrict__ topc, const float* __restrict__ ct,
    const float* __restrict__ cbstep, const float* __restrict__ xtg,
    const _Float16* __restrict__ wAh, const _Float16* __restrict__ wAl,
    const _Float16* __restrict__ woh, const _Float16* __restrict__ wol,
    const float* __restrict__ b1a, const float* __restrict__ b2a,
    const float* __restrict__ bout,
    float* __restrict__ cand, float* __restrict__ d2g)
{
  __shared__ _Float16 hhi[WM * 256], hlo[WM * 256];   // 64 KB (h and u, in place)
  __shared__ float xs[DD];
  __shared__ float pd2[WM][8];
  __shared__ int   cl[WM];

  int tid = threadIdx.x;
  int l = tid & 63, w = tid >> 6;          // w in [0,16)
  int lg = l >> 4, lr = l & 15;
  int bf0 = blockIdx.x * 8;               // 8 beam elems per block
  int b = bf0 >> 4;
  const f32x4 z4 = {0.f, 0.f, 0.f, 0.f};

  if (tid < WM) cl[tid] = topc[bf0 * AA + tid];
  if (tid < DD) xs[tid] = x[b * DD + tid];
  __syncthreads();

  // ---- h_init[m][j] = ct[cl[m]][j] + xtg[bf0 + (m>>3)][j], split into LDS
  for (int i = 0; i < 16; ++i) {
    int e = tid + i * 1024;
    int m = e >> 8, j = e & 255;
    float v = ct[cl[m] * HH + j] + xtg[(size_t)(bf0 + (m >> 3)) * 256 + j];
    _Float16 hi = (_Float16)v;
    int off = hoff(m, j);
    hhi[off] = hi;
    hlo[off] = (_Float16)((v - (float)hi) * 2048.0f);
  }
  __syncthreads();

  // column ownership: wave w -> coltile w of N=256
  int j0 = w * 16 + lr;

  // ---- residual layers (h and u share one LDS buffer, in place)
  for (int lay = 0; lay < 2; ++lay) {
    const _Float16* W1h = wAh + (size_t)(lay * 2 + 0) * 65536;
    const _Float16* W1l = wAl + (size_t)(lay * 2 + 0) * 65536;
    const _Float16* W2h = wAh + (size_t)(lay * 2 + 1) * 65536;
    const _Float16* W2l = wAl + (size_t)(lay * 2 + 1) * 65536;

    // GEMM1: u = relu(h @ W1 + b1); acc[rt]
    f32x4 a1[4], a2[4];
#pragma unroll
    for (int rt = 0; rt < 4; ++rt) { a1[rt] = z4; a2[rt] = z4; }
    for (int q = 0; q < 8; ++q) {
      size_t boff = ((size_t)(q * 16 + w) * 64 + l) * 8;
      f16x8 Bh = *(const f16x8*)&W1h[boff];
      f16x8 Bl = *(const f16x8*)&W1l[boff];
#pragma unroll
      for (int rt = 0; rt < 4; ++rt) {
        int arow = rt * 16 + lr;
        int aoff = arow * 256 + (((q * 4 + lg) ^ (arow & 7)) << 3);
        f16x8 Ah = *(f16x8*)&hhi[aoff];
        f16x8 Al = *(f16x8*)&hlo[aoff];
        a1[rt] = __builtin_amdgcn_mfma_f32_16x16x32_f16(Ah, Bh, a1[rt], 0, 0, 0);
        a2[rt] = __builtin_amdgcn_mfma_f32_16x16x32_f16(Al, Bh, a2[rt], 0, 0, 0);
        a2[rt] = __builtin_amdgcn_mfma_f32_16x16x32_f16(Ah, Bl, a2[rt], 0, 0, 0);
      }
    }
    // epilogue: a1 := relu(u), a2 := res (read from h before overwrite)
    {
      float bj = b1a[lay * HH + j0];
#pragma unroll
      for (int rt = 0; rt < 4; ++rt)
#pragma unroll
        for (int r = 0; r < 4; ++r) {
          int m = rt * 16 + lg * 4 + r;
          float u = fmaxf(a1[rt][r] + a2[rt][r] * (1.0f / 2048.0f) + bj, 0.f);
          int off = hoff(m, j0);
          float res = (float)hhi[off] + (float)hlo[off] * (1.0f / 2048.0f);
          a1[rt][r] = u;
          a2[rt][r] = res;
        }
    }
    __syncthreads();   // all reads of h done
#pragma unroll
    for (int rt = 0; rt < 4; ++rt)
#pragma unroll
      for (int r = 0; r < 4; ++r) {
        int m = rt * 16 + lg * 4 + r;
        float v = a1[rt][r];
        _Float16 hi = (_Float16)v;
        int off = hoff(m, j0);
        hhi[off] = hi;
        hlo[off] = (_Float16)((v - (float)hi) * 2048.0f);
      }
    __syncthreads();   // u visible

    // GEMM2: h' = res + u @ W2 + b2 ; acc init a1 = res
#pragma unroll
    for (int rt = 0; rt < 4; ++rt) {
      a1[rt] = a2[rt];
      a2[rt] = z4;
    }
    for (int q = 0; q < 8; ++q) {
      size_t boff = ((size_t)(q * 16 + w) * 64 + l) * 8;
      f16x8 Bh = *(const f16x8*)&W2h[boff];
      f16x8 Bl = *(const f16x8*)&W2l[boff];
#pragma unroll
      for (int rt = 0; rt < 4; ++rt) {
        int arow = rt * 16 + lr;
        int aoff = arow * 256 + (((q * 4 + lg) ^ (arow & 7)) << 3);
        f16x8 Ah = *(f16x8*)&hhi[aoff];
        f16x8 Al = *(f16x8*)&hlo[aoff];
        a1[rt] = __builtin_amdgcn_mfma_f32_16x16x32_f16(Ah, Bh, a1[rt], 0, 0, 0);
        a2[rt] = __builtin_amdgcn_mfma_f32_16x16x32_f16(Al, Bh, a2[rt], 0, 0, 0);
        a2[rt] = __builtin_amdgcn_mfma_f32_16x16x32_f16(Ah, Bl, a2[rt], 0, 0, 0);
      }
    }
    // epilogue: a1 := h'
    {
      float bj = b2a[lay * HH + j0];
#pragma unroll
      for (int rt = 0; rt < 4; ++rt)
#pragma unroll
        for (int r = 0; r < 4; ++r)
          a1[rt][r] += a2[rt][r] * (1.0f / 2048.0f) + bj;
    }
    __syncthreads();   // all reads of u done
#pragma unroll
    for (int rt = 0; rt < 4; ++rt)
#pragma unroll
      for (int r = 0; r < 4; ++r) {
        int m = rt * 16 + lg * 4 + r;
        float v = a1[rt][r];
        _Float16 hi = (_Float16)v;
        int off = hoff(m, j0);
        hhi[off] = hi;
        hlo[off] = (_Float16)((v - (float)hi) * 2048.0f);
      }
    __syncthreads();   // h' visible
  }

  // ---- out stage: cand = h @ W_out + b_out + cw_res + xhat; d2 scoring
  // N=128 -> coltile c8 = w&7; row-half mh = w>>3 covers rts {2mh, 2mh+1}
  int c8 = w & 7, mh = w >> 3;
  f32x4 o1[2], o2[2];
  o1[0] = z4; o1[1] = z4; o2[0] = z4; o2[1] = z4;
  for (int q = 0; q < 8; ++q) {
    size_t boff = ((size_t)(q * 8 + c8) * 64 + l) * 8;
    f16x8 Bh = *(const f16x8*)&woh[boff];
    f16x8 Bl = *(const f16x8*)&wol[boff];
#pragma unroll
    for (int rr = 0; rr < 2; ++rr) {
      int arow = (mh * 2 + rr) * 16 + lr;
      int aoff = arow * 256 + (((q * 4 + lg) ^ (arow & 7)) << 3);
      f16x8 Ah = *(f16x8*)&hhi[aoff];
      f16x8 Al = *(f16x8*)&hlo[aoff];
      o1[rr] = __builtin_amdgcn_mfma_f32_16x16x32_f16(Ah, Bh, o1[rr], 0, 0, 0);
      o2[rr] = __builtin_amdgcn_mfma_f32_16x16x32_f16(Al, Bh, o2[rr], 0, 0, 0);
      o2[rr] = __builtin_amdgcn_mfma_f32_16x16x32_f16(Ah, Bl, o2[rr], 0, 0, 0);
    }
  }
  int ci0 = (blockIdx.x & 1) * WM;
  int d = c8 * 16 + lr;
  float bo = bout[d];
  float xsd = xs[d];
#pragma unroll
  for (int rr = 0; rr < 2; ++rr) {
    int rt = mh * 2 + rr;
    float p[4];
#pragma unroll
    for (int r = 0; r < 4; ++r) {
      int m = rt * 16 + lg * 4 + r;
      float v = o1[rr][r] + o2[rr][r] * (1.0f / 2048.0f) + bo
              + cbstep[(size_t)cl[m] * DD + d]
              + xhat[(size_t)(bf0 + (m >> 3)) * DD + d];
      cand[((size_t)(b * 128 + ci0 + m)) * DD + d] = v;
      p[r] = v * (v - 2.f * xsd);
    }
#pragma unroll
    for (int mk = 1; mk < 16; mk <<= 1) {
#pragma unroll
      for (int r = 0; r < 4; ++r) p[r] += __shfl_xor(p[r], mk);
    }
    if (lr == 0) {
#pragma unroll
      for (int r = 0; r < 4; ++r) pd2[rt * 16 + lg * 4 + r][c8] = p[r];
    }
  }
  __syncthreads();
  if (tid < WM) {
    float s = 0.f;
#pragma unroll
    for (int ww = 0; ww < 8; ++ww) s += pd2[tid][ww];
    d2g[b * 128 + ci0 + tid] = s;
  }
}

// --------------------------- per-step: top-F_out prune + gather update
__global__ __launch_bounds__(64) void topk_update_kernel(
    const float* __restrict__ d2g, const float* __restrict__ cand,
    const int* __restrict__ codes_in, const int* __restrict__ topc,
    float* __restrict__ xhat_out, int* __restrict__ codes_out,
    int fout, int spos)
{
  int b = blockIdx.x, lane = threadIdx.x;
  float v0 = d2g[b * 128 + lane];
  float v1 = d2g[b * 128 + 64 + lane];
  for (int r = 0; r < fout; ++r) {
    float bv = v0; int bi = lane;
    if (v1 < bv) { bv = v1; bi = 64 + lane; }
#pragma unroll
    for (int mmk = 1; mmk < 64; mmk <<= 1) {
      float ov = __shfl_xor(bv, mmk);
      int   oi = __shfl_xor(bi, mmk);
      if (ov < bv || (ov == bv && oi < bi)) { bv = ov; bi = oi; }
    }
    int parent = bi >> 3, a = bi & 7;
    if (lane < MM) {
      int valc = (lane == spos) ? topc[(b * BEAMW + parent) * AA + a]
                                : codes_in[(b * BEAMW + parent) * MM + lane];
      codes_out[(b * BEAMW + r) * MM + lane] = valc;
    }
    const float* src = cand + ((size_t)(b * 128 + bi)) * DD;
    float2 t = *(const float2*)(src + lane * 2);
    *(float2*)(xhat_out + (size_t)(b * BEAMW + r) * DD + lane * 2) = t;
    if (bi < 64) { if (lane == bi) v0 = FLT_MAX; }
    else         { if (lane == bi - 64) v1 = FLT_MAX; }
  }
}

// ---------------------------------------------------------------- output
__global__ __launch_bounds__(64) void finalize_kernel(
    const int* __restrict__ codes_fin, const float* __restrict__ xhat_fin,
    float* __restrict__ out)
{
  int b = blockIdx.x, lane = threadIdx.x;
  float2 t = *(const float2*)(xhat_fin + (size_t)(b * BEAMW) * DD + lane * 2);
  *(float2*)(out + (size_t)MM * BB + (size_t)b * DD + lane * 2) = t;
  if (lane < MM) out[lane * BB + b] = (float)codes_fin[(b * BEAMW) * MM + lane];
}

extern "C" void kernel_launch(void* const* d_in, const int* in_sizes, int n_in,
                              void* d_out, int out_size, void* d_ws, size_t ws_size,
                              hipStream_t stream)
{
  (void)in_sizes; (void)n_in; (void)out_size; (void)ws_size;
  const float* x    = (const float*)d_in[0];
  const float* cb   = (const float*)d_in[1];
  const float* rq   = (const float*)d_in[2];
  const float* Win  = (const float*)d_in[3];
  const float* bin  = (const float*)d_in[4];
  const float* Wcat = (const float*)d_in[5];
  const float* bcat = (const float*)d_in[6];
  const float* W1   = (const float*)d_in[7];
  const float* b1   = (const float*)d_in[8];
  const float* W2   = (const float*)d_in[9];
  const float* b2   = (const float*)d_in[10];
  const float* Wout = (const float*)d_in[11];
  const float* bout = (const float*)d_in[12];
  float* out = (float*)d_out;

  char* ws = (char*)d_ws;
  size_t off = 0;
  auto alloc = [&](size_t bytes) -> void* {
    void* p = ws + off;
    off += (bytes + 255) & ~(size_t)255;
    return p;
  };
  float* X0    = (float*)alloc((size_t)BB * BEAMW * DD * 4);
  float* X1    = (float*)alloc((size_t)BB * BEAMW * DD * 4);
  int*   C0    = (int*)  alloc((size_t)BB * BEAMW * MM * 4);
  int*   C1    = (int*)  alloc((size_t)BB * BEAMW * MM * 4);
  int*   tc    = (int*)  alloc((size_t)BB * BEAMW * AA * 4);
  float* d2b   = (float*)alloc((size_t)BB * 128 * 4);
  float* candb = (float*)alloc((size_t)BB * 128 * DD * 4);
  float* xtg   = (float*)alloc((size_t)BB * BEAMW * 256 * 4);
  float* rqT7  = (float*)alloc((size_t)SS * DD * KK * 4);
  float* rqn7  = (float*)alloc((size_t)SS * KK * 4);
  float* ct7   = (float*)alloc((size_t)SS * KK * HH * 4);
  _Float16* wAh7 = (_Float16*)alloc((size_t)SS * 4 * 65536 * 2);
  _Float16* wAl7 = (_Float16*)alloc((size_t)SS * 4 * 65536 * 2);
  _Float16* woh7 = (_Float16*)alloc((size_t)SS * 32768 * 2);
  _Float16* wol7 = (_Float16*)alloc((size_t)SS * 32768 * 2);
  _Float16* wch7 = (_Float16*)alloc((size_t)SS * 32768 * 2);
  _Float16* wcl7 = (_Float16*)alloc((size_t)SS * 32768 * 2);

  // step-independent prep for ALL steps, upfront
  wpack_kernel<<<(SS * 40960) / 256, 256, 0, stream>>>(
      W1, W2, Wout, Wcat, wAh7, wAl7, woh7, wol7, wch7, wcl7);
  rqprep_kernel<<<SS * KK, DD, 0, stream>>>(rq, rqT7, rqn7);
  codeterm_kernel<<<SS * KK, HH, 0, stream>>>(cb, Win, bin, Wcat, bcat, ct7);

  step0_kernel<<<BB, 64, 0, stream>>>(x, cb, X0, C0);
  float* Xc = X0; float* Xn = X1;
  int* Cc = C0; int* Cn = C1;
  for (int s = 0; s < SS; ++s) {
    prefilter_kernel<<<(BB * BEAMW) / 32, 256, 0, stream>>>(
        x, Xc, rqT7 + (size_t)s * DD * KK, rqn7 + (size_t)s * KK, tc);
    xterm_kernel<<<(BB * BEAMW) / 16, 256, 0, stream>>>(
        Xc, wch7 + (size_t)s * 32768, wcl7 + (size_t)s * 32768, xtg);
    mlp_kernel<<<(BB * BEAMW * AA) / WM, 1024, 0, stream>>>(
        x, Xc, tc, ct7 + (size_t)s * KK * HH,
        cb + (size_t)(s + 1) * KK * DD, xtg,
        wAh7 + (size_t)s * 262144, wAl7 + (size_t)s * 262144,
        woh7 + (size_t)s * 32768, wol7 + (size_t)s * 32768,
        b1 + (size_t)s * 2 * HH, b2 + (size_t)s * 2 * HH,
        bout + (size_t)s * DD,
        candb, d2b);
    int fo = (s < SS - 1) ? BEAMW : 1;
    topk_update_kernel<<<BB, 64, 0, stream>>>(d2b, candb, Cc, tc, Xn, Cn, fo, s + 1);
    { float* t = Xc; Xc = Xn; Xn = t; }
    { int* t = Cc; Cc = Cn; Cn = t; }
  }
  finalize_kernel<<<BB, 64, 0, stream>>>(Cc, Xc, out);
}